// Round 5
// baseline (234.865 us; speedup 1.0000x reference)
//
#include <hip/hip_runtime.h>

#define KNB 8
#define OCC_R 0.25f
#define BIGF 1e30f

__device__ __forceinline__ float med3f(float a, float b, float c) {
#if defined(__has_builtin) && __has_builtin(__builtin_amdgcn_fmed3f)
    return __builtin_amdgcn_fmed3f(a, b, c);   // single v_med3_f32
#else
    return fmaxf(fminf(a, b), fminf(fmaxf(a, b), c));
#endif
}

// Unconditional parallel insert of x into sorted-ascending b0..b7 (drops old b7).
// In-place reverse order: each line reads only lower-indexed OLD values.
#define INS8(val) { float x = (val);          \
    b7 = med3f(b6, b7, x);                    \
    b6 = med3f(b5, b6, x);                    \
    b5 = med3f(b4, b5, x);                    \
    b4 = med3f(b3, b4, x);                    \
    b3 = med3f(b2, b3, x);                    \
    b2 = med3f(b1, b2, x);                    \
    b1 = med3f(b0, b1, x);                    \
    b0 = fminf(b0, x); }

// ---------------- kernel 1: prep targets -> (-2x, -2y, -2z, x^2+y^2+z^2)
__global__ void prep_targets(const float* __restrict__ tc, float4* __restrict__ out, int M) {
    int j = blockIdx.x * blockDim.x + threadIdx.x;
    if (j >= M) return;
    float x = tc[3 * j + 0];
    float y = tc[3 * j + 1];
    float z = tc[3 * j + 2];
    float k2 = x * x + y * y + z * z;
    out[j] = make_float4(-2.0f * x, -2.0f * y, -2.0f * z, k2);
}

// ---------------- kernel 2: per-query top-8 (squared distances) over a target chunk.
// Targets are read with WAVE-UNIFORM indices -> compiler emits scalar s_load into
// SGPRs (constant-cache pipe), freeing the LDS/DS pipe entirely.
__global__ __launch_bounds__(256) void knn_partial(
    const float* __restrict__ tf,     // to_filter, N x 6
    const float4* __restrict__ tgt,   // prepped targets, M
    float* __restrict__ part,         // N x split x 8 (squared dists, sorted asc)
    int N, int M) {
    int q = blockIdx.x * blockDim.x + threadIdx.x;   // query index
    int s = blockIdx.y;                               // split index
    int nspl = gridDim.y;
    int chunk = M / nspl;
    int c0 = s * chunk;

    float qx = tf[6 * q + 0];
    float qy = tf[6 * q + 1];
    float qz = tf[6 * q + 2];
    float q2 = qx * qx + qy * qy + qz * qz;

    float b0 = BIGF, b1 = BIGF, b2 = BIGF, b3 = BIGF;
    float b4 = BIGF, b5 = BIGF, b6 = BIGF, b7 = BIGF;

    #pragma unroll 8
    for (int t = c0; t < c0 + chunk; ++t) {
        float4 c = tgt[t];                   // uniform address -> s_load
        float d2 = q2 + c.w;                 // q2 + k2
        d2 = fmaf(c.x, qx, d2);              // -2 kx * qx
        d2 = fmaf(c.y, qy, d2);
        d2 = fmaf(c.z, qz, d2);
        INS8(d2);
    }

    float* p = part + ((size_t)q * nspl + s) * KNB;
    ((float4*)p)[0] = make_float4(b0, b1, b2, b3);
    ((float4*)p)[1] = make_float4(b4, b5, b6, b7);
}

// ---------------- kernel 3: merge split partial lists, sqrt, mask, store
__global__ void knn_merge(const float* __restrict__ part, float* __restrict__ out,
                          int N, int split) {
    int q = blockIdx.x * blockDim.x + threadIdx.x;
    if (q >= N) return;
    const float4* p = (const float4*)(part + (size_t)q * split * KNB);
    float4 v0 = p[0];
    float4 v1 = p[1];
    float b0 = v0.x, b1 = v0.y, b2 = v0.z, b3 = v0.w;
    float b4 = v1.x, b5 = v1.y, b6 = v1.z, b7 = v1.w;
    for (int s = 1; s < split; ++s) {
        float4 u0 = p[2 * s];
        float4 u1 = p[2 * s + 1];
        INS8(u0.x); INS8(u0.y); INS8(u0.z); INS8(u0.w);
        INS8(u1.x); INS8(u1.y); INS8(u1.z); INS8(u1.w);
    }
    float d0 = sqrtf(fmaxf(b0, 0.0f));
    float d1 = sqrtf(fmaxf(b1, 0.0f));
    float d2_ = sqrtf(fmaxf(b2, 0.0f));
    float d3 = sqrtf(fmaxf(b3, 0.0f));
    float d4 = sqrtf(fmaxf(b4, 0.0f));
    float d5 = sqrtf(fmaxf(b5, 0.0f));
    float d6 = sqrtf(fmaxf(b6, 0.0f));
    float d7 = sqrtf(fmaxf(b7, 0.0f));
    bool good = d0 > OCC_R;
    float m = good ? 1.0f : 0.0f;
    float4* o = (float4*)(out + (size_t)q * KNB);
    o[0] = make_float4(d0 * m, d1 * m, d2_ * m, d3 * m);
    o[1] = make_float4(d4 * m, d5 * m, d6 * m, d7 * m);
}

extern "C" void kernel_launch(void* const* d_in, const int* in_sizes, int n_in,
                              void* d_out, int out_size, void* d_ws, size_t ws_size,
                              hipStream_t stream) {
    const float* tf = (const float*)d_in[0];   // to_filter (N x 6)
    const float* tc = (const float*)d_in[1];   // target_coords (M x 3)
    int N = in_sizes[0] / 6;                   // 32768
    int M = in_sizes[1] / 3;                   // 16384
    float* outp = (float*)d_out;

    char* ws = (char*)d_ws;
    size_t tgt_bytes = ((size_t)M * 16 + 255) & ~(size_t)255;
    float4* tgt = (float4*)ws;
    float* part = (float*)(ws + tgt_bytes);

    int split = 4;
    while (split > 1 && ws_size < tgt_bytes + (size_t)N * split * KNB * 4) split >>= 1;

    prep_targets<<<(M + 255) / 256, 256, 0, stream>>>(tc, tgt, M);
    dim3 grid(N / 256, split);
    knn_partial<<<grid, 256, 0, stream>>>(tf, tgt, part, N, M);
    knn_merge<<<(N + 255) / 256, 256, 0, stream>>>(part, outp, N, split);
}

// Round 6
// 158.779 us; speedup vs baseline: 1.4792x; 1.4792x over previous
//
#include <hip/hip_runtime.h>

#define KNB 8
#define OCC_R 0.25f
#define BIGF 1e30f

__device__ __forceinline__ float med3f(float a, float b, float c) {
#if defined(__has_builtin) && __has_builtin(__builtin_amdgcn_fmed3f)
    return __builtin_amdgcn_fmed3f(a, b, c);   // single v_med3_f32
#else
    return fmaxf(fminf(a, b), fminf(fmaxf(a, b), c));
#endif
}

// Unconditional parallel insert of x into sorted-ascending b0..b7 (drops old b7).
// In-place reverse order: each line reads only lower-indexed OLD values.
#define INS8(val) { float x = (val);          \
    b7 = med3f(b6, b7, x);                    \
    b6 = med3f(b5, b6, x);                    \
    b5 = med3f(b4, b5, x);                    \
    b4 = med3f(b3, b4, x);                    \
    b3 = med3f(b2, b3, x);                    \
    b2 = med3f(b1, b2, x);                    \
    b1 = med3f(b0, b1, x);                    \
    b0 = fminf(b0, x); }

// ---------------- kernel 1: prep targets -> (-2x, -2y, -2z, x^2+y^2+z^2)
__global__ void prep_targets(const float* __restrict__ tc, float4* __restrict__ out, int M) {
    int j = blockIdx.x * blockDim.x + threadIdx.x;
    if (j >= M) return;
    float x = tc[3 * j + 0];
    float y = tc[3 * j + 1];
    float z = tc[3 * j + 2];
    float k2 = x * x + y * y + z * z;
    out[j] = make_float4(-2.0f * x, -2.0f * y, -2.0f * z, k2);
}

// ---------------- kernel 2: per-query top-8 (squared distances) over a target chunk.
// Targets are read with WAVE-UNIFORM indices -> scalar s_load into SGPRs
// (constant-cache pipe). split=16 -> 2048 blocks = 8 blocks/CU = 32 waves/CU
// so s_load latency is hidden by thread-level parallelism.
__global__ __launch_bounds__(256) void knn_partial(
    const float* __restrict__ tf,     // to_filter, N x 6
    const float4* __restrict__ tgt,   // prepped targets, M
    float* __restrict__ part,         // N x split x 8 (squared dists, sorted asc)
    int N, int M) {
    int q = blockIdx.x * blockDim.x + threadIdx.x;   // query index
    int s = blockIdx.y;                               // split index
    int nspl = gridDim.y;
    int chunk = M / nspl;
    int c0 = s * chunk;

    float qx = tf[6 * q + 0];
    float qy = tf[6 * q + 1];
    float qz = tf[6 * q + 2];
    float q2 = qx * qx + qy * qy + qz * qz;

    float b0 = BIGF, b1 = BIGF, b2 = BIGF, b3 = BIGF;
    float b4 = BIGF, b5 = BIGF, b6 = BIGF, b7 = BIGF;

    #pragma unroll 8
    for (int t = c0; t < c0 + chunk; ++t) {
        float4 c = tgt[t];                   // uniform address -> s_load
        float d2 = q2 + c.w;                 // q2 + k2
        d2 = fmaf(c.x, qx, d2);              // -2 kx * qx
        d2 = fmaf(c.y, qy, d2);
        d2 = fmaf(c.z, qz, d2);
        INS8(d2);
    }

    float* p = part + ((size_t)q * nspl + s) * KNB;
    ((float4*)p)[0] = make_float4(b0, b1, b2, b3);
    ((float4*)p)[1] = make_float4(b4, b5, b6, b7);
}

// ---------------- kernel 3: merge split partial lists, sqrt, mask, store
__global__ void knn_merge(const float* __restrict__ part, float* __restrict__ out,
                          int N, int split) {
    int q = blockIdx.x * blockDim.x + threadIdx.x;
    if (q >= N) return;
    const float4* p = (const float4*)(part + (size_t)q * split * KNB);
    float4 v0 = p[0];
    float4 v1 = p[1];
    float b0 = v0.x, b1 = v0.y, b2 = v0.z, b3 = v0.w;
    float b4 = v1.x, b5 = v1.y, b6 = v1.z, b7 = v1.w;
    for (int s = 1; s < split; ++s) {
        float4 u0 = p[2 * s];
        float4 u1 = p[2 * s + 1];
        INS8(u0.x); INS8(u0.y); INS8(u0.z); INS8(u0.w);
        INS8(u1.x); INS8(u1.y); INS8(u1.z); INS8(u1.w);
    }
    float d0 = sqrtf(fmaxf(b0, 0.0f));
    float d1 = sqrtf(fmaxf(b1, 0.0f));
    float d2_ = sqrtf(fmaxf(b2, 0.0f));
    float d3 = sqrtf(fmaxf(b3, 0.0f));
    float d4 = sqrtf(fmaxf(b4, 0.0f));
    float d5 = sqrtf(fmaxf(b5, 0.0f));
    float d6 = sqrtf(fmaxf(b6, 0.0f));
    float d7 = sqrtf(fmaxf(b7, 0.0f));
    bool good = d0 > OCC_R;
    float m = good ? 1.0f : 0.0f;
    float4* o = (float4*)(out + (size_t)q * KNB);
    o[0] = make_float4(d0 * m, d1 * m, d2_ * m, d3 * m);
    o[1] = make_float4(d4 * m, d5 * m, d6 * m, d7 * m);
}

extern "C" void kernel_launch(void* const* d_in, const int* in_sizes, int n_in,
                              void* d_out, int out_size, void* d_ws, size_t ws_size,
                              hipStream_t stream) {
    const float* tf = (const float*)d_in[0];   // to_filter (N x 6)
    const float* tc = (const float*)d_in[1];   // target_coords (M x 3)
    int N = in_sizes[0] / 6;                   // 32768
    int M = in_sizes[1] / 3;                   // 16384
    float* outp = (float*)d_out;

    char* ws = (char*)d_ws;
    size_t tgt_bytes = ((size_t)M * 16 + 255) & ~(size_t)255;
    float4* tgt = (float4*)ws;
    float* part = (float*)(ws + tgt_bytes);

    // split=16 -> grid 128x16 = 2048 blocks = 8 blocks/CU (full 32 waves/CU).
    int split = 16;
    while (split > 1 && ws_size < tgt_bytes + (size_t)N * split * KNB * 4) split >>= 1;

    prep_targets<<<(M + 255) / 256, 256, 0, stream>>>(tc, tgt, M);
    dim3 grid(N / 256, split);
    knn_partial<<<grid, 256, 0, stream>>>(tf, tgt, part, N, M);
    knn_merge<<<(N + 255) / 256, 256, 0, stream>>>(part, outp, N, split);
}

// Round 7
// 155.260 us; speedup vs baseline: 1.5127x; 1.0227x over previous
//
#include <hip/hip_runtime.h>

#define KNB 8
#define OCC_R 0.25f
#define BIGF 1e30f
#define GRP 8

__device__ __forceinline__ float med3f(float a, float b, float c) {
#if defined(__has_builtin) && __has_builtin(__builtin_amdgcn_fmed3f)
    return __builtin_amdgcn_fmed3f(a, b, c);   // single v_med3_f32
#else
    return fmaxf(fminf(a, b), fminf(fmaxf(a, b), c));
#endif
}

// Unconditional parallel insert of x into sorted-ascending b0..b7 (drops old b7).
// In-place reverse order: each line reads only lower-indexed OLD values.
#define INS8(val) { float x = (val);          \
    b7 = med3f(b6, b7, x);                    \
    b6 = med3f(b5, b6, x);                    \
    b5 = med3f(b4, b5, x);                    \
    b4 = med3f(b3, b4, x);                    \
    b3 = med3f(b2, b3, x);                    \
    b2 = med3f(b1, b2, x);                    \
    b1 = med3f(b0, b1, x);                    \
    b0 = fminf(b0, x); }

// distance + insert for one candidate float4
#define PAIR(c) {                             \
    float d2 = q2 + (c).w;                    \
    d2 = fmaf((c).x, qx, d2);                 \
    d2 = fmaf((c).y, qy, d2);                 \
    d2 = fmaf((c).z, qz, d2);                 \
    INS8(d2); }

#define PROCESS(arr) {                        \
    _Pragma("unroll")                         \
    for (int j = 0; j < GRP; ++j) { float4 c = (arr)[j]; PAIR(c); } }

// ---------------- kernel 1: prep targets -> (-2x, -2y, -2z, x^2+y^2+z^2)
__global__ void prep_targets(const float* __restrict__ tc, float4* __restrict__ out, int M) {
    int j = blockIdx.x * blockDim.x + threadIdx.x;
    if (j >= M) return;
    float x = tc[3 * j + 0];
    float y = tc[3 * j + 1];
    float z = tc[3 * j + 2];
    float k2 = x * x + y * y + z * z;
    out[j] = make_float4(-2.0f * x, -2.0f * y, -2.0f * z, k2);
}

// ---------------- kernel 2: per-query top-8 (squared distances) over a target chunk.
// Wave-uniform target reads -> scalar s_load into SGPRs. Depth-2 software
// pipeline: load candidate group g+1 into SGPR regs while the 13-VALU/candidate
// ladder processes group g, so the ~200cy K$/L2 latency hides under compute.
__global__ __launch_bounds__(256) void knn_partial(
    const float* __restrict__ tf,     // to_filter, N x 6
    const float4* __restrict__ tgt,   // prepped targets, M
    float* __restrict__ part,         // N x split x 8 (squared dists, sorted asc)
    int N, int M) {
    int q = blockIdx.x * blockDim.x + threadIdx.x;   // query index
    int s = blockIdx.y;                               // split index
    int nspl = gridDim.y;
    int chunk = M / nspl;                             // 1024 at split=16
    const float4* __restrict__ g = tgt + s * chunk;   // wave-uniform base

    float qx = tf[6 * q + 0];
    float qy = tf[6 * q + 1];
    float qz = tf[6 * q + 2];
    float q2 = qx * qx + qy * qy + qz * qz;

    float b0 = BIGF, b1 = BIGF, b2 = BIGF, b3 = BIGF;
    float b4 = BIGF, b5 = BIGF, b6 = BIGF, b7 = BIGF;

    float4 ca[GRP], cb[GRP];
    #pragma unroll
    for (int j = 0; j < GRP; ++j) ca[j] = g[j];

    int ngrp = chunk / GRP;                           // even (chunk % 16 == 0)
    for (int grp = 0; grp < ngrp - 2; grp += 2) {
        #pragma unroll
        for (int j = 0; j < GRP; ++j) cb[j] = g[(grp + 1) * GRP + j];
        PROCESS(ca);
        #pragma unroll
        for (int j = 0; j < GRP; ++j) ca[j] = g[(grp + 2) * GRP + j];
        PROCESS(cb);
    }
    // tail pair of groups
    #pragma unroll
    for (int j = 0; j < GRP; ++j) cb[j] = g[(ngrp - 1) * GRP + j];
    PROCESS(ca);
    PROCESS(cb);

    float* p = part + ((size_t)q * nspl + s) * KNB;
    ((float4*)p)[0] = make_float4(b0, b1, b2, b3);
    ((float4*)p)[1] = make_float4(b4, b5, b6, b7);
}

// ---------------- kernel 3: merge split partial lists, sqrt, mask, store
__global__ void knn_merge(const float* __restrict__ part, float* __restrict__ out,
                          int N, int split) {
    int q = blockIdx.x * blockDim.x + threadIdx.x;
    if (q >= N) return;
    const float4* p = (const float4*)(part + (size_t)q * split * KNB);
    float4 v0 = p[0];
    float4 v1 = p[1];
    float b0 = v0.x, b1 = v0.y, b2 = v0.z, b3 = v0.w;
    float b4 = v1.x, b5 = v1.y, b6 = v1.z, b7 = v1.w;
    for (int s = 1; s < split; ++s) {
        float4 u0 = p[2 * s];
        float4 u1 = p[2 * s + 1];
        INS8(u0.x); INS8(u0.y); INS8(u0.z); INS8(u0.w);
        INS8(u1.x); INS8(u1.y); INS8(u1.z); INS8(u1.w);
    }
    float d0 = sqrtf(fmaxf(b0, 0.0f));
    float d1 = sqrtf(fmaxf(b1, 0.0f));
    float d2_ = sqrtf(fmaxf(b2, 0.0f));
    float d3 = sqrtf(fmaxf(b3, 0.0f));
    float d4 = sqrtf(fmaxf(b4, 0.0f));
    float d5 = sqrtf(fmaxf(b5, 0.0f));
    float d6 = sqrtf(fmaxf(b6, 0.0f));
    float d7 = sqrtf(fmaxf(b7, 0.0f));
    bool good = d0 > OCC_R;
    float m = good ? 1.0f : 0.0f;
    float4* o = (float4*)(out + (size_t)q * KNB);
    o[0] = make_float4(d0 * m, d1 * m, d2_ * m, d3 * m);
    o[1] = make_float4(d4 * m, d5 * m, d6 * m, d7 * m);
}

extern "C" void kernel_launch(void* const* d_in, const int* in_sizes, int n_in,
                              void* d_out, int out_size, void* d_ws, size_t ws_size,
                              hipStream_t stream) {
    const float* tf = (const float*)d_in[0];   // to_filter (N x 6)
    const float* tc = (const float*)d_in[1];   // target_coords (M x 3)
    int N = in_sizes[0] / 6;                   // 32768
    int M = in_sizes[1] / 3;                   // 16384
    float* outp = (float*)d_out;

    char* ws = (char*)d_ws;
    size_t tgt_bytes = ((size_t)M * 16 + 255) & ~(size_t)255;
    float4* tgt = (float4*)ws;
    float* part = (float*)(ws + tgt_bytes);

    // split=16 -> grid 128x16 = 2048 blocks = 8 blocks/CU (full 32 waves/CU).
    int split = 16;
    while (split > 1 && ws_size < tgt_bytes + (size_t)N * split * KNB * 4) split >>= 1;

    prep_targets<<<(M + 255) / 256, 256, 0, stream>>>(tc, tgt, M);
    dim3 grid(N / 256, split);
    knn_partial<<<grid, 256, 0, stream>>>(tf, tgt, part, N, M);
    knn_merge<<<(N + 255) / 256, 256, 0, stream>>>(part, outp, N, split);
}